// Round 6
// baseline (161.095 us; speedup 1.0000x reference)
//
#include <hip/hip_runtime.h>
#include <hip/hip_bf16.h>
#include <stdint.h>

#define B_  2
#define S_  2048
#define H_  512
#define NH_ 8
#define DK_ 64

typedef __bf16 bf16x8 __attribute__((ext_vector_type(8)));
typedef short  s16x4  __attribute__((ext_vector_type(4)));
typedef float  f32x4  __attribute__((ext_vector_type(4)));

static __device__ __forceinline__ uint32_t pk2(float a, float b) {
  __hip_bfloat162 h = __float22bfloat162_rn(float2{a, b});
  uint32_t u;
  __builtin_memcpy(&u, &h, 4);
  return u;
}

// 16x16x16 bf16 MFMA. Guard with __HIP_DEVICE_COMPILE__ (host pass lacks
// device builtins — R3 compile failure).
static __device__ __forceinline__ f32x4 mfma_k16(s16x4 a, s16x4 b, f32x4 c) {
#if defined(__HIP_DEVICE_COMPILE__)
  return __builtin_amdgcn_mfma_f32_16x16x16bf16_1k(a, b, c, 0, 0, 0);
#else
  (void)a; (void)b;
  return c;
#endif
}

typedef const __attribute__((address_space(1))) uint32_t* gas_t;
typedef __attribute__((address_space(3))) uint32_t* las_t;
static __device__ __forceinline__ void cp16(const void* g, void* l) {
  __builtin_amdgcn_global_load_lds((gas_t)g, (las_t)l, 16, 0, 0);
}

// ---------------------------------------------------------------------------
// R13 prep split. Kernel A: bias zero-scan (blocks 0..511) + one-time
// f32->bf16 convert of X (query/key/value) and W (blocks 512..943) + fmL
// (944). Kernel B: proj GEMM on pre-converted bf16 with global_load_lds
// direct staging (pre-swizzled global source, linear LDS dest — same XOR'd
// layout + fragment reads as R11, so MFMA/epilogue logic is unchanged).
// Removes the per-K-step f32 reg round-trip + 32 cvt + 16 ds_write that made
// the old fused proj staging-VALU-bound (m90-pattern ~330 TF).
// ---------------------------------------------------------------------------
struct PrepArgs {
  const float* X[3];
  const float* W[3];
  uint16_t*    Xb[3];
  uint16_t*    Wb[3];
  const float* bias;
  const int*   mask;
  uint32_t*    zrow;
  float*       fmL;
};

__global__ __launch_bounds__(256) void prep_a_kernel(PrepArgs pa) {
  __shared__ uint32_t wbuf[8][4];
  int bid = blockIdx.x, t = threadIdx.x;

  if (bid < 512) {
    // ---- bias zero-scan: 8 (b,q) rows per block, loads pipelined ----
    int rr = bid;                            // 0..511
    const float* base = pa.bias + (size_t)rr * 8 * 2048 + t * 8;
    uint4 a[8], b2[8];
#pragma unroll
    for (int i = 0; i < 8; i++) {
      const uint4* src = (const uint4*)(base + (size_t)i * 2048);
      a[i] = src[0]; b2[i] = src[1];
    }
    int wv = t >> 6, ln = t & 63;
#pragma unroll
    for (int i = 0; i < 8; i++) {
      bool z = ((a[i].x << 1) == 0u) | ((a[i].y << 1) == 0u) |
               ((a[i].z << 1) == 0u) | ((a[i].w << 1) == 0u) |
               ((b2[i].x << 1) == 0u) | ((b2[i].y << 1) == 0u) |
               ((b2[i].z << 1) == 0u) | ((b2[i].w << 1) == 0u);
      uint64_t m = __ballot(z);
      if (ln == 0) {
        uint32_t bits = 0;
#pragma unroll
        for (int c = 0; c < 8; c++)
          bits |= (uint32_t)(((m >> (8 * c)) & 0xFFull) != 0ull) << c;
        wbuf[i][wv] = bits;                  // chunks [wv*8, wv*8+8)
      }
    }
    __syncthreads();
    if (t < 8)
      pa.zrow[rr * 8 + t] = wbuf[t][0] | (wbuf[t][1] << 8) |
                            (wbuf[t][2] << 16) | (wbuf[t][3] << 24);
  } else if (bid < 944) {
    // ---- f32 -> bf16 convert: 16384 elems (64 KB read) per block ----
    int cid = bid - 512;                     // 0..431
    const float* src; uint16_t* dst; size_t off;
    if (cid < 384) {                         // X: 3 x 2,097,152 elems
      int mat = cid >> 7;                    // 128 blocks per mat
      off = (size_t)(cid & 127) * 16384;
      src = pa.X[mat]; dst = pa.Xb[mat];
    } else {                                 // W: 3 x 262,144 elems
      int c2 = cid - 384;
      int mat = c2 >> 4;                     // 16 blocks per mat
      off = (size_t)(c2 & 15) * 16384;
      src = pa.W[mat]; dst = pa.Wb[mat];
    }
    const float* s = src + off;
    uint16_t*    d = dst + off;
#pragma unroll
    for (int i = 0; i < 8; i++) {
      size_t e = (size_t)i * 2048 + t * 8;
      float4 x0 = *(const float4*)(s + e);
      float4 x1 = *(const float4*)(s + e + 4);
      uint4 o4;
      o4.x = pk2(x0.x, x0.y); o4.y = pk2(x0.z, x0.w);
      o4.z = pk2(x1.x, x1.y); o4.w = pk2(x1.z, x1.w);
      *(uint4*)(d + e) = o4;
    }
  } else {
    // ---- fmL = mask * log2(e) ----
    const float LOG2E = 1.44269504088896340736f;
#pragma unroll
    for (int i = 0; i < 16; i++) {
      int idx = i * 256 + t;
      pa.fmL[idx] = (float)pa.mask[idx] * LOG2E;
    }
  }
}

// ---------------------------------------------------------------------------
// Kernel B: proj GEMM, tile 128 s x 128 d, bf16 in via DMA staging.
// XCD swizzle: all 4 dtiles of group gi share bid%8 -> same XCD L2.
// Per K-step (BK=64): 8 cp16 (X-tile 16KB + W-tile 16KB across 4 waves) +
// 20 ds_read_b128 + 32 MFMA. LDS image identical to R11's packed layout:
// row-major [row][64], physical 16B seg p holds logical seg p^(row&7)
// (achieved by pre-swizzling the GLOBAL source seg: (l&7)^(l>>3)).
// ---------------------------------------------------------------------------
struct GemmArgs {
  const uint16_t* Xb[3];
  const uint16_t* Wb[3];
  const float*    Bv[3];
  uint16_t*       O[3];
};

__global__ __launch_bounds__(256) void proj_kernel(GemmArgs ga) {
  __shared__ __align__(16) char psm[65536];   // 2 bufs x (Xs 16KB | Ws 16KB)
  int bid = blockIdx.x, t = threadIdx.x;
  int xcd = bid & 7, j = bid >> 3;             // j in 0..47
  int gi = ((j >> 2) << 3) | xcd;              // group 0..95
  int dtile = j & 3;
  int mat = gi >> 5, mtile = gi & 31;
  int m0 = mtile * 128, n0 = dtile * 128;
  const uint16_t* X  = ga.Xb[mat];
  const uint16_t* Wt = ga.Wb[mat];
  const float*    Bv = ga.Bv[mat];
  uint16_t*       O  = ga.O[mat];

  int w = t >> 6, l = t & 63, lo = l & 15, g = l >> 4;

  // staging: lane l -> row (w*32 + i*8 + (l>>3)), physical seg l&7;
  // global col seg pre-swizzled: (l&7)^(l>>3)  [row&7 == l>>3].
  int lr8 = l >> 3;
  int lsg = (l & 7) ^ lr8;
  const uint16_t* xsrc = X  + (size_t)(m0 + w * 32 + lr8) * 512 + lsg * 8;
  const uint16_t* wsrc = Wt + (size_t)(n0 + w * 32 + lr8) * 512 + lsg * 8;

  f32x4 acc[2][8];
#pragma unroll
  for (int st = 0; st < 2; st++)
#pragma unroll
    for (int dt = 0; dt < 8; dt++) acc[st][dt] = (f32x4){0.f, 0.f, 0.f, 0.f};

  auto stage = [&](int kb, int buf) {
    char* base = psm + buf * 32768;
    int co = kb * 64;
#pragma unroll
    for (int i = 0; i < 4; i++) {
      cp16(xsrc + (size_t)i * 8 * 512 + co, base + (w * 32 + i * 8) * 128);
      cp16(wsrc + (size_t)i * 8 * 512 + co, base + 16384 + (w * 32 + i * 8) * 128);
    }
  };

  stage(0, 0);

  for (int kb = 0; kb < 8; kb++) {
    int cur = kb & 1;
    asm volatile("s_waitcnt vmcnt(0)" ::: "memory");
    __builtin_amdgcn_s_barrier();              // publish tile kb
    if (kb < 7) stage(kb + 1, cur ^ 1);        // in flight across compute
    __builtin_amdgcn_sched_barrier(0);

    const uint16_t* Xs = (const uint16_t*)(psm + cur * 32768);
    const uint16_t* Ws = (const uint16_t*)(psm + cur * 32768 + 16384);

#pragma unroll
    for (int kk = 0; kk < 2; kk++) {
      int seg = (kk * 4 + g) ^ (lo & 7);
      bf16x8 xf[2], wf[8];
#pragma unroll
      for (int st = 0; st < 2; st++)
        xf[st] = *(const bf16x8*)(Xs + (w * 32 + st * 16 + lo) * 64 + seg * 8);
#pragma unroll
      for (int dt = 0; dt < 8; dt++)
        wf[dt] = *(const bf16x8*)(Ws + (dt * 16 + lo) * 64 + seg * 8);
      if (mat < 2) {
#pragma unroll
        for (int st = 0; st < 2; st++)
#pragma unroll
          for (int dt = 0; dt < 8; dt++)
            acc[st][dt] = __builtin_amdgcn_mfma_f32_16x16x32_bf16(wf[dt], xf[st], acc[st][dt], 0, 0, 0);
      } else {
#pragma unroll
        for (int st = 0; st < 2; st++)
#pragma unroll
          for (int dt = 0; dt < 8; dt++)
            acc[st][dt] = __builtin_amdgcn_mfma_f32_16x16x32_bf16(xf[st], wf[dt], acc[st][dt], 0, 0, 0);
      }
    }
  }

  if (mat < 2) {
    float scale = (mat == 0) ? 0.125f : 1.0f;
    float4 bv4[8];
#pragma unroll
    for (int dt = 0; dt < 8; dt++)
      bv4[dt] = *(const float4*)(Bv + n0 + dt * 16 + g * 4);
#pragma unroll
    for (int st = 0; st < 2; st++) {
      int ss = m0 + w * 32 + st * 16 + lo;
      int bb = ss >> 11, sIn = ss & 2047;
#pragma unroll
      for (int dt = 0; dt < 8; dt++) {
        int h2 = dtile * 2 + (dt >> 2);        // output head
        uint16_t* op = O + ((size_t)(bb * NH_ + h2) * S_ + sIn) * DK_ +
                       (dt & 3) * 16 + g * 4;
        float v0 = (acc[st][dt][0] + bv4[dt].x) * scale;
        float v1 = (acc[st][dt][1] + bv4[dt].y) * scale;
        float v2 = (acc[st][dt][2] + bv4[dt].z) * scale;
        float v3 = (acc[st][dt][3] + bv4[dt].w) * scale;
        uint2 pk{pk2(v0, v1), pk2(v2, v3)};
        *(uint2*)op = pk;
      }
    }
  } else {
    float bval[8];
#pragma unroll
    for (int dt = 0; dt < 8; dt++) bval[dt] = Bv[n0 + dt * 16 + lo];
#pragma unroll
    for (int st = 0; st < 2; st++) {
      int m = m0 + w * 32 + st * 16 + g * 4;
      int bb = m >> 11, sIn = m & 2047;
#pragma unroll
      for (int dt = 0; dt < 8; dt++) {
        int h2 = dtile * 2 + (dt >> 2);        // output head
        int dd = (dt & 3) * 16 + lo;
        float v0 = acc[st][dt][0] + bval[dt];
        float v1 = acc[st][dt][1] + bval[dt];
        float v2 = acc[st][dt][2] + bval[dt];
        float v3 = acc[st][dt][3] + bval[dt];
        uint2 pk{pk2(v0, v1), pk2(v2, v3)};
        *(uint2*)(O + ((size_t)(bb * NH_ + h2) * DK_ + dd) * S_ + sIn) = pk;
      }
    }
  }
}

// ---------------------------------------------------------------------------
// Kernel 2: flash attention — UNCHANGED from R12 (five structural variants
// all land 41-44 us; parked). q-tile 64, grid 512, triple-buffered K/V,
// counted vmcnt(4), fm in LDS, ones-MFMA row-sum.
// ---------------------------------------------------------------------------
__global__ __launch_bounds__(256) void attn_kernel(
    const uint16_t* __restrict__ Qb, const uint16_t* __restrict__ Kb,
    const uint16_t* __restrict__ Vt, const uint32_t* __restrict__ zrow,
    const float* __restrict__ fmL, const float* __restrict__ bias,
    float* __restrict__ out) {
  int bid = blockIdx.x;
  int bh = bid & 15, qtile = bid >> 4;   // 512 blocks: bid%8 const per bh
  int b = bh >> 3, h = bh & 7;
  int q0 = qtile * 64;
  int t = threadIdx.x;
  int w = t >> 6, l = t & 63, lo = l & 15, g = l >> 4;

  // buf i at smem + i*16384: K[64][64] (8KB) | V[64][64] (8KB); fm at 49152.
  __shared__ __align__(16) char smem[57344];

  const uint16_t* Qh = Qb + (size_t)bh * S_ * DK_;
  const uint16_t* Kh = Kb + (size_t)bh * S_ * DK_;
  const uint16_t* Vh = Vt + (size_t)bh * DK_ * S_;

  // DMA: lane l -> LDS row w*16 + l/8, seg l&7; global seg = (l&7)^(row&7).
  int lrow = l >> 3, lseg = (l & 7) ^ lrow;
  const uint16_t* kbase = Kh + (size_t)(w * 16 + lrow) * DK_ + lseg * 8;
  const uint16_t* vbase = Vh + (size_t)(w * 16 + lrow) * S_ + lseg * 8;
  int kdo = w * 2048;          // K half dst byte offset (wave-uniform)
  int vdo = 8192 + w * 2048;   // V half

  // fm preload: 8 KB = 2 cp16 per wave (first cp16s issued: oldest ledger
  // entries, retired by the first vmcnt(4)).
  float* fmlds = (float*)(smem + 49152);
  const float* fmG = fmL + b * S_;
  cp16(fmG + w * 256 + l * 4, smem + 49152 + w * 1024);
  cp16(fmG + 1024 + w * 256 + l * 4, smem + 49152 + 4096 + w * 1024);

  // stage tiles 0 and 1 (distance-2 prologue)
  auto stage = [&](const uint16_t* kp, const uint16_t* vp, uint32_t bufo) {
    cp16(kp, smem + bufo + kdo);
    cp16(kp + 512, smem + bufo + kdo + 1024);
    cp16(vp, smem + bufo + vdo);
    cp16(vp + 8 * S_, smem + bufo + vdo + 1024);
  };
  stage(kbase, vbase, 0);
  stage(kbase + 4096, vbase + 64, 16384);
  const uint16_t* kpS = kbase + 8192;   // running src for stage(kb+2)
  const uint16_t* vpS = vbase + 128;

  // block-uniform zero-bias mask (OR over this block's 64 q rows)
  uint32_t zall = zrow[(b << 11) + q0 + l];
#pragma unroll
  for (int s = 1; s < 64; s <<= 1) zall |= __shfl_xor(zall, s);

  // Register-resident Q fragments (B-operand of QK), 4 q-subtiles x K=64.
  bf16x8 qf[4][2];
#pragma unroll
  for (int qt = 0; qt < 4; qt++)
#pragma unroll
    for (int kk = 0; kk < 2; kk++)
      qf[qt][kk] = *(const bf16x8*)(Qh + (size_t)(q0 + qt * 16 + lo) * DK_ + kk * 32 + g * 8);

  f32x4 o[4][4];
#pragma unroll
  for (int dt = 0; dt < 4; dt++)
#pragma unroll
    for (int qt = 0; qt < 4; qt++) o[dt][qt] = (f32x4){0.f, 0.f, 0.f, 0.f};
  f32x4 tsa[4];
#pragma unroll
  for (int qt = 0; qt < 4; qt++) tsa[qt] = (f32x4){0.f, 0.f, 0.f, 0.f};
  const s16x4 vone = {(short)0x3F80, (short)0x3F80, (short)0x3F80, (short)0x3F80};

  const float LOG2E = 1.44269504088896340736f;

  uint32_t oA = 0, oB = 16384, oC = 32768;   // compute / in-flight / stage

  for (int kb = 0; kb < 32; kb++) {
    int k0 = kb * 64;
    // steady state: 8 cp16 outstanding (tiles kb, kb+1). vmcnt(4) retires
    // tile kb; tile kb+1 stays in flight across the barrier and compute.
    if (kb < 31) asm volatile("s_waitcnt vmcnt(4)" ::: "memory");
    else         asm volatile("s_waitcnt vmcnt(0)" ::: "memory");
    __builtin_amdgcn_s_barrier();               // publish tile kb to all waves
    if (kb + 2 < 32) {                          // stage tile kb+2
      stage(kpS, vpS, oC);
      kpS += 4096; vpS += 64;
    }
    __builtin_amdgcn_sched_barrier(0);          // pin: no ds_read above barrier

    const uint16_t* KsT = (const uint16_t*)(smem + oA);
    const uint16_t* VsT = (const uint16_t*)(smem + oA + 8192);

    // V^T A-frags for PV
    s16x4 vf[4];
    {
      int s = (2 * w + (g >> 1)) ^ (lo & 7);
      int off = s * 8 + (g & 1) * 4;
#pragma unroll
      for (int dt = 0; dt < 4; dt++)
        vf[dt] = *(const s16x4*)(VsT + (dt * 16 + lo) * 64 + off);
    }
    // K A-frags (this wave's 16 k-rows)
    bf16x8 kf[2];
#pragma unroll
    for (int kk = 0; kk < 2; kk++) {
      int s = (kk * 4 + g) ^ (lo & 7);
      kf[kk] = *(const bf16x8*)(KsT + (w * 16 + lo) * 64 + s * 8);
    }

    // S^T = K * Q^T : lane holds S[k = w*16+g*4+r][q = qt*16+lo]
    f32x4 c[4];
#pragma unroll
    for (int qt = 0; qt < 4; qt++) {
      f32x4 z = {0.f, 0.f, 0.f, 0.f};
      z = __builtin_amdgcn_mfma_f32_16x16x32_bf16(kf[0], qf[qt][0], z, 0, 0, 0);
      c[qt] = __builtin_amdgcn_mfma_f32_16x16x32_bf16(kf[1], qf[qt][1], z, 0, 0, 0);
    }

    float4 mv4 = *(const float4*)(fmlds + kb * 64 + w * 16 + g * 4);
    s16x4 pf[4];
    if (((zall >> kb) & 1u) == 0u) {   // no zero bias in this 64k chunk
#pragma unroll
      for (int qt = 0; qt < 4; qt++) {
        float p0 = __builtin_amdgcn_exp2f(__builtin_fmaf(c[qt][0], LOG2E, mv4.x));
        float p1 = __builtin_amdgcn_exp2f(__builtin_fmaf(c[qt][1], LOG2E, mv4.y));
        float p2 = __builtin_amdgcn_exp2f(__builtin_fmaf(c[qt][2], LOG2E, mv4.z));
        float p3 = __builtin_amdgcn_exp2f(__builtin_fmaf(c[qt][3], LOG2E, mv4.w));
        union { s16x4 v; uint32_t u[2]; } uu;
        uu.u[0] = pk2(p0, p1);
        uu.u[1] = pk2(p2, p3);
        pf[qt] = uu.v;
      }
    } else {                           // rare: bias==0 -> weight 0
#pragma unroll
      for (int qt = 0; qt < 4; qt++) {
        float4 bz = *(const float4*)(bias + ((size_t)(b * S_ + q0 + qt * 16 + lo)) * S_ + k0 + w * 16 + g * 4);
        float p0 = (bz.x == 0.f) ? 0.f : __builtin_amdgcn_exp2f(__builtin_fmaf(c[qt][0], LOG2E, mv4.x));
        float p1 = (bz.y == 0.f) ? 0.f : __builtin_amdgcn_exp2f(__builtin_fmaf(c[qt][1], LOG2E, mv4.y));
        float p2 = (bz.z == 0.f) ? 0.f : __builtin_amdgcn_exp2f(__builtin_fmaf(c[qt][2], LOG2E, mv4.z));
        float p3 = (bz.w == 0.f) ? 0.f : __builtin_amdgcn_exp2f(__builtin_fmaf(c[qt][3], LOG2E, mv4.w));
        union { s16x4 v; uint32_t u[2]; } uu;
        uu.u[0] = pk2(p0, p1);
        uu.u[1] = pk2(p2, p3);
        pf[qt] = uu.v;
      }
    }

    // row-sum via matrix pipe: tsa[qt][r] = sum_k pf[k][q=lo] (all r equal)
#pragma unroll
    for (int qt = 0; qt < 4; qt++)
      tsa[qt] = mfma_k16(vone, pf[qt], tsa[qt]);

    // PV: o[dt][qt] lane holds O[q=qt*16+lo][d=dt*16+g*4+r]
#pragma unroll
    for (int dt = 0; dt < 4; dt++)
#pragma unroll
      for (int qt = 0; qt < 4; qt++)
        o[dt][qt] = mfma_k16(vf[dt], pf[qt], o[dt][qt]);

    // rotate buffers
    uint32_t tmp = oA; oA = oB; oB = oC; oC = tmp;
  }

  // ---- epilogue: reduce 4 wave-partials, normalize, store (2 q-halves) ----
  float* OT = (float*)smem;               // [64 d][33] floats (8448 B)
  float* LS = (float*)(smem + 8448);      // [4 w][4 qt][16 lo] (1 KB)
  __syncthreads();                        // main-loop LDS reads complete
  if (g == 0) {
#pragma unroll
    for (int qt = 0; qt < 4; qt++) LS[(w * 4 + qt) * 16 + lo] = tsa[qt][0];
  }
#pragma unroll
  for (int qh = 0; qh < 2; qh++) {
#pragma unroll
    for (int ww = 0; ww < 4; ww++) {
      if (w == ww) {
#pragma unroll
        for (int dt = 0; dt < 4; dt++)
#pragma unroll
          for (int qt = 0; qt < 2; qt++)
#pragma unroll
            for (int r = 0; r < 4; r++) {
              int idx = (dt * 16 + g * 4 + r) * 33 + qt * 16 + lo;
              float val = o[dt][qh * 2 + qt][r];
              if (ww == 0) OT[idx] = val;
              else         OT[idx] += val;
            }
      }
      __syncthreads();
    }
    {
      int q = t >> 3, dseg = (t & 7) * 8;   // q in [0,32), 8 d per thread
      int qt2 = qh * 2 + (q >> 4), lo2 = q & 15;
      float lsum = LS[(0 * 4 + qt2) * 16 + lo2] + LS[(1 * 4 + qt2) * 16 + lo2] +
                   LS[(2 * 4 + qt2) * 16 + lo2] + LS[(3 * 4 + qt2) * 16 + lo2];
      float linv = 1.0f / fmaxf(lsum, 1e-30f);
      float* ob = out + ((size_t)(b * S_ + q0 + qh * 32 + q)) * H_ + h * DK_ + dseg;
#pragma unroll
      for (int i = 0; i < 2; i++) {
        float4 v;
        v.x = OT[(dseg + i * 4 + 0) * 33 + q] * linv;
        v.y = OT[(dseg + i * 4 + 1) * 33 + q] * linv;
        v.z = OT[(dseg + i * 4 + 2) * 33 + q] * linv;
        v.w = OT[(dseg + i * 4 + 3) * 33 + q] * linv;
        *(float4*)(ob + i * 4) = v;
      }
    }
    __syncthreads();                      // OT reads done before next overwrite
  }
}

// ---------------------------------------------------------------------------
extern "C" void kernel_launch(void* const* d_in, const int* in_sizes, int n_in,
                              void* d_out, int out_size, void* d_ws, size_t ws_size,
                              hipStream_t stream) {
  const float* query = (const float*)d_in[0];
  const float* key   = (const float*)d_in[1];
  const float* value = (const float*)d_in[2];
  const float* bias  = (const float*)d_in[3];
  const int*   mask  = (const int*)d_in[4];
  const float* Wq = (const float*)d_in[5];
  const float* bq = (const float*)d_in[6];
  const float* Wk = (const float*)d_in[7];
  const float* bk = (const float*)d_in[8];
  const float* Wv = (const float*)d_in[9];
  const float* bv = (const float*)d_in[10];

  char* ws = (char*)d_ws;
  uint32_t* zrow = (uint32_t*)ws;                             // 16 KB
  float*    fmL  = (float*)(ws + 16384);                      // 16 KB
  uint16_t* Qb = (uint16_t*)(ws + (size_t)(1 << 20));         // 4 MB
  uint16_t* Kb = (uint16_t*)(ws + (size_t)(5 << 20));         // 4 MB
  uint16_t* Vt = (uint16_t*)(ws + (size_t)(9 << 20));         // 4 MB
  uint16_t* Xb0 = (uint16_t*)(ws + (size_t)(16 << 20));       // 4 MB each
  uint16_t* Xb1 = (uint16_t*)(ws + (size_t)(20 << 20));
  uint16_t* Xb2 = (uint16_t*)(ws + (size_t)(24 << 20));
  uint16_t* Wb0 = (uint16_t*)(ws + (size_t)(28 << 20));       // 512 KB each
  uint16_t* Wb1 = (uint16_t*)(ws + (size_t)(29 << 20));
  uint16_t* Wb2 = (uint16_t*)(ws + (size_t)(30 << 20));

  PrepArgs pa;
  pa.X[0] = query; pa.X[1] = key; pa.X[2] = value;
  pa.W[0] = Wq;    pa.W[1] = Wk;  pa.W[2] = Wv;
  pa.Xb[0] = Xb0;  pa.Xb[1] = Xb1; pa.Xb[2] = Xb2;
  pa.Wb[0] = Wb0;  pa.Wb[1] = Wb1; pa.Wb[2] = Wb2;
  pa.bias = bias;  pa.mask = mask;
  pa.zrow = zrow;  pa.fmL = fmL;

  GemmArgs ga;
  ga.Xb[0] = Xb0; ga.Xb[1] = Xb1; ga.Xb[2] = Xb2;
  ga.Wb[0] = Wb0; ga.Wb[1] = Wb1; ga.Wb[2] = Wb2;
  ga.Bv[0] = bq;  ga.Bv[1] = bk;  ga.Bv[2] = bv;
  ga.O[0] = Qb;   ga.O[1] = Kb;   ga.O[2] = Vt;

  prep_a_kernel<<<945, 256, 0, stream>>>(pa);
  proj_kernel<<<384, 256, 0, stream>>>(ga);
  attn_kernel<<<512, 256, 0, stream>>>(Qb, Kb, Vt, zrow, fmL, bias, (float*)d_out);
}